// Round 1
// baseline (70.068 us; speedup 1.0000x reference)
//
#include <hip/hip_runtime.h>

#define PAGE     64
#define LSEQ     8192
#define BROWS    32
#define MAXPAGES 8192
#define MP64     (MAXPAGES * PAGE)   // 524288 slots per row

// element offsets (int32 elements) into flat d_out, reference return order:
// token_valid, page_indices, page_valid, segment_ids, token2page
#define OFF_TV   0
#define OFF_PI   (BROWS * LSEQ)                        // 262144
#define OFF_PV   (OFF_PI + BROWS * MP64)               // 17039360
#define OFF_SI   (OFF_PV + BROWS * MP64)               // 33816576
#define OFF_T2P  (OFF_SI + BROWS * MAXPAGES)           // 34078720

// Fill the contiguous PI|PV|SI region: PI=-1, PV=0, SI=-1. 16B vector stores.
__global__ void SegmentPager_fill(int4* __restrict__ p) {
    const long long PI4  = (long long)BROWS * MP64 / 4;        // 4,194,304
    const long long PV4e = PI4 * 2;                            // 8,388,608
    const long long N4   = PV4e + (long long)BROWS * MAXPAGES / 4; // 8,454,144
    long long stride = (long long)gridDim.x * blockDim.x;
    for (long long i = (long long)blockIdx.x * blockDim.x + threadIdx.x;
         i < N4; i += stride) {
        int v = (i < PI4 || i >= PV4e) ? -1 : 0;
        p[i] = make_int4(v, v, v, v);
    }
}

__global__ __launch_bounds__(256) void SegmentPager_pager(
        const int* __restrict__ ids,
        const int* __restrict__ mask,
        const int* __restrict__ qpos,
        int* __restrict__ out) {
    __shared__ unsigned char sSt[LSEQ];     // segment-start flag per token
    __shared__ int sStarts[LSEQ + 2];       // compact start positions (ordered)
    __shared__ int sTst[LSEQ + 2];          // fill position at segment start
    __shared__ int sMeta[2];                // [0]=nseg, [1]=any_valid

    const int row = blockIdx.x;
    const int tid = threadIdx.x;
    int qp = qpos[row];
    qp = qp < 0 ? 0 : (qp > LSEQ ? LSEQ : qp);

    const int* idr = ids  + (size_t)row * LSEQ;
    const int* mkr = mask + (size_t)row * LSEQ;

    if (tid < 2) sMeta[tid] = 0;
    __syncthreads();

    // Phase 1: segment-start flags + any_valid
    int myany = 0;
    for (int i = tid; i < LSEQ; i += 256) {
        int fl = (i == 0) || (i == qp);
        if (i > 0 && idr[i - 1] == 13) fl = 1;
        sSt[i] = (unsigned char)fl;
        myany |= (mkr[i] != 0);
    }
    if (myany) sMeta[1] = 1;   // benign race: all writers store 1
    __syncthreads();

    // Phase 2 (wave 0): ordered compaction of start positions, then serial
    // scan over segments computing Tstart (fill position after optional flush).
    if (tid < 64) {
        int count = 0;
        for (int base = 0; base < LSEQ; base += 64) {
            bool f = sSt[base + tid] != 0;
            unsigned long long bal = __ballot(f);
            if (f) {
                int pre = __popcll(bal & ((1ull << tid) - 1ull));
                sStarts[count + pre] = base + tid;
            }
            count += __popcll(bal);
        }
        // serial over segments (uniform across lanes; lane 0 writes)
        int T = 0;
        for (int s = 0; s < count; ++s) {
            int p  = sStarts[s];
            int pn = (s + 1 < count) ? sStarts[s + 1] : LSEQ;
            int sl = pn - p;
            int c  = T & (PAGE - 1);
            if (c > 0 && (p == qp || sl > PAGE - c)) T += PAGE - c;  // flush pad
            if (tid == 0) sTst[s] = T;
            T += sl;
        }
        if (tid == 0) sMeta[0] = count;
    }
    __syncthreads();

    const int nseg = sMeta[0];
    const int av   = sMeta[1];

    int* tv  = out + OFF_TV  + (size_t)row * LSEQ;
    int* t2p = out + OFF_T2P + (size_t)row * LSEQ;
    int* pi  = out + OFF_PI  + (size_t)row * MP64;
    int* pv  = out + OFF_PV  + (size_t)row * MP64;
    int* si  = out + OFF_SI  + (size_t)row * MAXPAGES;

    // Phase 3: per-token outputs. T is monotone in i -> near-coalesced scatter.
    for (int i = tid; i < LSEQ; i += 256) {
        int lo = 0, hi = nseg - 1;
        while (lo < hi) {                       // largest s with starts[s] <= i
            int mid = (lo + hi + 1) >> 1;
            if (sStarts[mid] <= i) lo = mid; else hi = mid - 1;
        }
        int T = sTst[lo] + (i - sStarts[lo]);
        int m = (mkr[i] != 0);
        tv[i]  = m;
        t2p[i] = av ? (T >> 6) : -1;
        if (av && T < MP64) {
            pi[T] = i;
            pv[T] = m;
            if ((T & (PAGE - 1)) == 0) si[T >> 6] = lo;  // page's first token
        }
    }
}

extern "C" void kernel_launch(void* const* d_in, const int* in_sizes, int n_in,
                              void* d_out, int out_size, void* d_ws, size_t ws_size,
                              hipStream_t stream) {
    const int* ids  = (const int*)d_in[0];
    const int* mask = (const int*)d_in[1];
    const int* qpos = (const int*)d_in[2];
    int* out = (int*)d_out;

    // Fill PI/PV/SI background (-1 / 0 / -1); TV and T2P are fully overwritten.
    SegmentPager_fill<<<2048, 256, 0, stream>>>((int4*)(out + OFF_PI));
    SegmentPager_pager<<<BROWS, 256, 0, stream>>>(ids, mask, qpos, out);
}

// Round 2
// 59.590 us; speedup vs baseline: 1.1758x; 1.1758x over previous
//
#include <hip/hip_runtime.h>

#define PAGE     64
#define LSEQ     8192
#define BROWS    32
#define MAXPAGES 8192
#define MP64     (MAXPAGES * PAGE)   // 524288 slots per row

// element offsets (int32 elements) into flat d_out, reference return order:
// token_valid, page_indices, page_valid, segment_ids, token2page
#define OFF_TV   0
#define OFF_PI   (BROWS * LSEQ)                        // 262144
#define OFF_PV   (OFF_PI + BROWS * MP64)               // 17039360
#define OFF_SI   (OFF_PV + BROWS * MP64)               // 33816576
#define OFF_T2P  (OFF_SI + BROWS * MAXPAGES)           // 34078720

// ws layout per row (ints): [0]=nseg [1]=any_valid [2]=Tend, starts @8, Tst @8+LSEQ+2
#define WROW       (8 + 2 * (LSEQ + 2))
#define WS_NEEDED  ((size_t)BROWS * WROW * sizeof(int))
#define SUBS       64                    // write-blocks per row
#define SLOTS_SUB  (MP64 / SUBS)         // 8192 PI/PV slots per block
#define PAGES_SUB  (MAXPAGES / SUBS)     // 128
#define TOK_SUB    (LSEQ / SUBS)         // 128
#define MAXSEG_LDS 2048

// ---------------- fast path ----------------

__global__ __launch_bounds__(256) void SegmentPager_setup(
        const int* __restrict__ ids,
        const int* __restrict__ mask,
        const int* __restrict__ qpos,
        int* __restrict__ ws) {
    __shared__ unsigned char sSt[LSEQ];
    __shared__ int sStarts[LSEQ + 2];
    __shared__ int sTst[LSEQ + 2];
    __shared__ int sMeta[4];             // [0]=nseg [1]=any_valid [2]=Tend

    const int row = blockIdx.x;
    const int tid = threadIdx.x;
    int qp = qpos[row];
    qp = qp < 0 ? 0 : (qp > LSEQ ? LSEQ : qp);

    const int* idr = ids  + (size_t)row * LSEQ;
    const int* mkr = mask + (size_t)row * LSEQ;
    int* wrow = ws + (size_t)row * WROW;

    if (tid < 4) sMeta[tid] = 0;
    __syncthreads();

    // Phase 1a: base flags (pos==0 | pos==qp)
    for (int i = tid; i < LSEQ; i += 256)
        sSt[i] = (unsigned char)((i == 0) | (i == qp));
    __syncthreads();
    // Phase 1b: newline flags (token i==13 -> start at i+1), vectorized; + any_valid
    int myany = 0;
    for (int g = tid; g < LSEQ / 4; g += 256) {
        int4 x = *(const int4*)(idr + g * 4);
        int4 m = *(const int4*)(mkr + g * 4);
        int b = g * 4;
        if (x.x == 13 && b + 1 < LSEQ) sSt[b + 1] = 1;
        if (x.y == 13 && b + 2 < LSEQ) sSt[b + 2] = 1;
        if (x.z == 13 && b + 3 < LSEQ) sSt[b + 3] = 1;
        if (x.w == 13 && b + 4 < LSEQ) sSt[b + 4] = 1;
        myany |= m.x | m.y | m.z | m.w;
    }
    if (myany) sMeta[1] = 1;   // benign all-write-1 race
    __syncthreads();

    // Phase 2 (wave 0): ordered compaction + serial segment scan
    if (tid < 64) {
        int count = 0;
        for (int base = 0; base < LSEQ; base += 64) {
            bool f = sSt[base + tid] != 0;
            unsigned long long bal = __ballot(f);
            if (f) {
                int pre = __popcll(bal & ((1ull << tid) - 1ull));
                sStarts[count + pre] = base + tid;
            }
            count += __popcll(bal);
        }
        int T = 0;
        for (int s = 0; s < count; ++s) {
            int p  = sStarts[s];
            int pn = (s + 1 < count) ? sStarts[s + 1] : LSEQ;
            int sl = pn - p;
            int c  = T & (PAGE - 1);
            if (c > 0 && (p == qp || sl > PAGE - c)) T += PAGE - c;  // flush pad
            if (tid == 0) sTst[s] = T;
            T += sl;
        }
        if (tid == 0) { sMeta[0] = count; sMeta[2] = T; }
    }
    __syncthreads();

    // Export tables
    const int count = sMeta[0];
    for (int j = tid; j < count; j += 256) {
        wrow[8 + j]              = sStarts[j];
        wrow[8 + (LSEQ + 2) + j] = sTst[j];
    }
    if (tid == 0) { wrow[0] = count; wrow[1] = sMeta[1]; wrow[2] = sMeta[2]; }
}

__global__ __launch_bounds__(256) void SegmentPager_write(
        const int* __restrict__ mask,
        const int* __restrict__ ws,
        int* __restrict__ out) {
    __shared__ int sS[MAXSEG_LDS + 1];
    __shared__ int sT[MAXSEG_LDS + 1];

    const int row = blockIdx.x >> 6;     // SUBS == 64
    const int sub = blockIdx.x & 63;
    const int tid = threadIdx.x;

    const int* wrow = ws + (size_t)row * WROW;
    const int nseg = wrow[0];
    const int av   = wrow[1];
    const int Tend = av ? wrow[2] : 0;   // degenerate row: everything background
    const int* gS = wrow + 8;
    const int* gT = wrow + 8 + (LSEQ + 2);

    const bool useLds = nseg <= MAXSEG_LDS;
    if (useLds)
        for (int j = tid; j < nseg; j += 256) { sS[j] = gS[j]; sT[j] = gT[j]; }
    __syncthreads();
    const int* S  = useLds ? (const int*)sS : gS;
    const int* Tt = useLds ? (const int*)sT : gT;
    const int* mkr = mask + (size_t)row * LSEQ;

    // ---- PI + PV: final values in one pass (no background fill kernel) ----
    int* pi = out + OFF_PI + (size_t)row * MP64;
    int* pv = out + OFF_PV + (size_t)row * MP64;
    const int Tbase = sub * SLOTS_SUB;
    for (int g = tid; g < SLOTS_SUB / 4; g += 256) {       // 8 iters
        int T = Tbase + g * 4;
        int4 vi = make_int4(-1, -1, -1, -1);
        int4 vv = make_int4(0, 0, 0, 0);
        if (T < Tend) {                                    // rare (used prefix)
            int r[4] = {-1, -1, -1, -1}, v[4] = {0, 0, 0, 0};
#pragma unroll
            for (int k = 0; k < 4; ++k) {
                int Tk = T + k;
                if (Tk < Tend) {
                    int lo = 0, hi = nseg - 1;
                    while (lo < hi) {                      // largest s: Tt[s] <= Tk
                        int mid = (lo + hi + 1) >> 1;
                        if (Tt[mid] <= Tk) lo = mid; else hi = mid - 1;
                    }
                    int pos  = S[lo] + (Tk - Tt[lo]);
                    int send = (lo + 1 < nseg) ? S[lo + 1] : LSEQ;
                    if (pos < send) { r[k] = pos; v[k] = (mkr[pos] != 0); }  // else pad slot
                }
            }
            vi = make_int4(r[0], r[1], r[2], r[3]);
            vv = make_int4(v[0], v[1], v[2], v[3]);
        }
        *(int4*)(pi + T) = vi;
        *(int4*)(pv + T) = vv;
    }

    // ---- SI: page p's segment = seg of slot 0 (always a token; pads only fill tails) ----
    if (tid < PAGES_SUB) {
        int p  = sub * PAGES_SUB + tid;
        int T0 = p * PAGE;
        int sid = -1;
        if (T0 < Tend) {
            int lo = 0, hi = nseg - 1;
            while (lo < hi) {
                int mid = (lo + hi + 1) >> 1;
                if (Tt[mid] <= T0) lo = mid; else hi = mid - 1;
            }
            sid = lo;
        }
        out[OFF_SI + (size_t)row * MAXPAGES + p] = sid;
    }

    // ---- TV + T2P ----
    if (tid < TOK_SUB) {
        int i = sub * TOK_SUB + tid;
        out[OFF_TV + (size_t)row * LSEQ + i] = (mkr[i] != 0);
        int t2 = -1;
        if (av) {
            int lo = 0, hi = nseg - 1;
            while (lo < hi) {                              // largest s: S[s] <= i
                int mid = (lo + hi + 1) >> 1;
                if (S[mid] <= i) lo = mid; else hi = mid - 1;
            }
            t2 = (Tt[lo] + (i - S[lo])) >> 6;
        }
        out[OFF_T2P + (size_t)row * LSEQ + i] = t2;
    }
}

// ---------------- fallback path (round-1, known-good) ----------------

__global__ void SegmentPager_fill(int4* __restrict__ p) {
    const long long PI4  = (long long)BROWS * MP64 / 4;
    const long long PV4e = PI4 * 2;
    const long long N4   = PV4e + (long long)BROWS * MAXPAGES / 4;
    long long stride = (long long)gridDim.x * blockDim.x;
    for (long long i = (long long)blockIdx.x * blockDim.x + threadIdx.x;
         i < N4; i += stride) {
        int v = (i < PI4 || i >= PV4e) ? -1 : 0;
        p[i] = make_int4(v, v, v, v);
    }
}

__global__ __launch_bounds__(256) void SegmentPager_pager(
        const int* __restrict__ ids,
        const int* __restrict__ mask,
        const int* __restrict__ qpos,
        int* __restrict__ out) {
    __shared__ unsigned char sSt[LSEQ];
    __shared__ int sStarts[LSEQ + 2];
    __shared__ int sTst[LSEQ + 2];
    __shared__ int sMeta[2];

    const int row = blockIdx.x;
    const int tid = threadIdx.x;
    int qp = qpos[row];
    qp = qp < 0 ? 0 : (qp > LSEQ ? LSEQ : qp);

    const int* idr = ids  + (size_t)row * LSEQ;
    const int* mkr = mask + (size_t)row * LSEQ;

    if (tid < 2) sMeta[tid] = 0;
    __syncthreads();

    int myany = 0;
    for (int i = tid; i < LSEQ; i += 256) {
        int fl = (i == 0) || (i == qp);
        if (i > 0 && idr[i - 1] == 13) fl = 1;
        sSt[i] = (unsigned char)fl;
        myany |= (mkr[i] != 0);
    }
    if (myany) sMeta[1] = 1;
    __syncthreads();

    if (tid < 64) {
        int count = 0;
        for (int base = 0; base < LSEQ; base += 64) {
            bool f = sSt[base + tid] != 0;
            unsigned long long bal = __ballot(f);
            if (f) {
                int pre = __popcll(bal & ((1ull << tid) - 1ull));
                sStarts[count + pre] = base + tid;
            }
            count += __popcll(bal);
        }
        int T = 0;
        for (int s = 0; s < count; ++s) {
            int p  = sStarts[s];
            int pn = (s + 1 < count) ? sStarts[s + 1] : LSEQ;
            int sl = pn - p;
            int c  = T & (PAGE - 1);
            if (c > 0 && (p == qp || sl > PAGE - c)) T += PAGE - c;
            if (tid == 0) sTst[s] = T;
            T += sl;
        }
        if (tid == 0) sMeta[0] = count;
    }
    __syncthreads();

    const int nseg = sMeta[0];
    const int av   = sMeta[1];

    int* tv  = out + OFF_TV  + (size_t)row * LSEQ;
    int* t2p = out + OFF_T2P + (size_t)row * LSEQ;
    int* pi  = out + OFF_PI  + (size_t)row * MP64;
    int* pv  = out + OFF_PV  + (size_t)row * MP64;
    int* si  = out + OFF_SI  + (size_t)row * MAXPAGES;

    for (int i = tid; i < LSEQ; i += 256) {
        int lo = 0, hi = nseg - 1;
        while (lo < hi) {
            int mid = (lo + hi + 1) >> 1;
            if (sStarts[mid] <= i) lo = mid; else hi = mid - 1;
        }
        int T = sTst[lo] + (i - sStarts[lo]);
        int m = (mkr[i] != 0);
        tv[i]  = m;
        t2p[i] = av ? (T >> 6) : -1;
        if (av && T < MP64) {
            pi[T] = i;
            pv[T] = m;
            if ((T & (PAGE - 1)) == 0) si[T >> 6] = lo;
        }
    }
}

// ---------------- launch ----------------

extern "C" void kernel_launch(void* const* d_in, const int* in_sizes, int n_in,
                              void* d_out, int out_size, void* d_ws, size_t ws_size,
                              hipStream_t stream) {
    const int* ids  = (const int*)d_in[0];
    const int* mask = (const int*)d_in[1];
    const int* qpos = (const int*)d_in[2];
    int* out = (int*)d_out;

    if (ws_size >= WS_NEEDED && d_ws != nullptr) {
        int* ws = (int*)d_ws;
        SegmentPager_setup<<<BROWS, 256, 0, stream>>>(ids, mask, qpos, ws);
        SegmentPager_write<<<BROWS * SUBS, 256, 0, stream>>>(mask, ws, out);
    } else {
        SegmentPager_fill<<<2048, 256, 0, stream>>>((int4*)(out + OFF_PI));
        SegmentPager_pager<<<BROWS, 256, 0, stream>>>(ids, mask, qpos, out);
    }
}

// Round 3
// 38.644 us; speedup vs baseline: 1.8132x; 1.5420x over previous
//
#include <hip/hip_runtime.h>

#define PAGE     64
#define LSEQ     8192
#define BROWS    32
#define MAXPAGES 8192
#define MP64     (MAXPAGES * PAGE)   // 524288 slots per row

// element offsets (int32 elements) into flat d_out, reference return order:
// token_valid, page_indices, page_valid, segment_ids, token2page
#define OFF_TV   0
#define OFF_PI   (BROWS * LSEQ)                        // 262144
#define OFF_PV   (OFF_PI + BROWS * MP64)               // 17039360
#define OFF_SI   (OFF_PV + BROWS * MP64)               // 33816576
#define OFF_T2P  (OFF_SI + BROWS * MAXPAGES)           // 34078720

// ws layout per row (ints): [0]=nseg [1]=any_valid [2]=Tend, starts @8, Tst @8+LSEQ+2
#define WROW       (8 + 2 * (LSEQ + 2))
#define WS_NEEDED  ((size_t)BROWS * WROW * sizeof(int))

// Tend < 2L + 64: each non-qp flush pad (64-c) < that segment's length (flush
// requires sl > 64-c), so sum(pads) < L; plus one qp flush <= 63.
#define TSAFE      16448
#define FOREPAGES  (TSAFE / PAGE)        // 257
#define CAPSEG     2048                  // LDS segment-table capacity

#define NBG        2016                  // background-fill blocks in mega
#define NFILL4     8454144               // int4 count of contiguous PI|PV|SI region
#define PI4END     (1 << 22)
#define PV4END     (1 << 23)

#define SUBS       8                     // fore blocks per row
#define SLOTS_SUB  (TSAFE / SUBS)        // 2056 (x4B = 8224, 16B aligned)
#define TOK_SUB    (LSEQ / SUBS)         // 1024

// ---------------- mega: setup (blocks 0..31) + background fill ----------------

__global__ __launch_bounds__(256) void SegmentPager_mega(
        const int* __restrict__ ids,
        const int* __restrict__ mask,
        const int* __restrict__ qpos,
        int* __restrict__ ws,
        int4* __restrict__ fillbase) {
    const int tid = threadIdx.x;

    if (blockIdx.x >= BROWS) {
        // ---- background: fill PI=-1, PV=0, SI=-1 over the contiguous region ----
        const int b = blockIdx.x - BROWS;
        const int stride = NBG * 256;
        for (int i = b * 256 + tid; i < NFILL4; i += stride) {
            int v = (i < PI4END || i >= PV4END) ? -1 : 0;
            fillbase[i] = make_int4(v, v, v, v);
        }
        return;
    }

    // ---- setup for row = blockIdx.x ----
    __shared__ unsigned int sBits[LSEQ / 32];   // 256 words: segment-start bitmask
    __shared__ int sS[CAPSEG + 1];
    __shared__ int sT[CAPSEG + 1];
    __shared__ int sMeta[4];                    // [0]=nseg [1]=any_valid [2]=Tend

    const int row = blockIdx.x;
    int qp = qpos[row];
    qp = qp < 0 ? 0 : (qp > LSEQ ? LSEQ : qp);

    const int* idr = ids  + (size_t)row * LSEQ;
    const int* mkr = mask + (size_t)row * LSEQ;
    int* wrow = ws + (size_t)row * WROW;

    sBits[tid] = 0u;                            // 256 threads zero 256 words
    if (tid < 4) sMeta[tid] = 0;
    __syncthreads();

    // Phase 1: sparse start-bits from vectorized id loads; any_valid
    int myany = 0;
    for (int g = tid; g < LSEQ / 4; g += 256) { // 8 iters
        int4 x = *(const int4*)(idr + g * 4);
        int4 m = *(const int4*)(mkr + g * 4);
        int b = g * 4;
        if (x.x == 13 && b + 1 < LSEQ) atomicOr(&sBits[(b + 1) >> 5], 1u << ((b + 1) & 31));
        if (x.y == 13 && b + 2 < LSEQ) atomicOr(&sBits[(b + 2) >> 5], 1u << ((b + 2) & 31));
        if (x.z == 13 && b + 3 < LSEQ) atomicOr(&sBits[(b + 3) >> 5], 1u << ((b + 3) & 31));
        if (x.w == 13 && b + 4 < LSEQ) atomicOr(&sBits[(b + 4) >> 5], 1u << ((b + 4) & 31));
        myany |= m.x | m.y | m.z | m.w;
    }
    if (tid == 0) {
        atomicOr(&sBits[0], 1u);
        if (qp < LSEQ) atomicOr(&sBits[qp >> 5], 1u << (qp & 31));
    }
    if (myany) sMeta[1] = 1;                    // benign all-write-1 race
    __syncthreads();

    // Phase 2 (wave 0): parallel ordered compaction of set bits
    if (tid < 64) {
        unsigned int w0 = sBits[4 * tid + 0];
        unsigned int w1 = sBits[4 * tid + 1];
        unsigned int w2 = sBits[4 * tid + 2];
        unsigned int w3 = sBits[4 * tid + 3];
        int cnt = __popc(w0) + __popc(w1) + __popc(w2) + __popc(w3);
        int off = cnt;                          // inclusive scan -> exclusive
        for (int d = 1; d < 64; d <<= 1) {
            int n = __shfl_up(off, d);
            if (tid >= d) off += n;
        }
        int total = __shfl(off, 63);
        off -= cnt;
        if (tid == 0) sMeta[0] = total;
        int* dst = (total <= CAPSEG) ? sS : (wrow + 8);
        unsigned int wd[4] = {w0, w1, w2, w3};
        int base = tid * 128;
#pragma unroll
        for (int w = 0; w < 4; ++w) {
            unsigned int word = wd[w];
            while (word) {
                int b = __ffs(word) - 1;
                word &= word - 1;
                dst[off++] = base + 32 * w + b;
            }
        }
    }
    __syncthreads();

    const int count = sMeta[0];
    const bool inLds = count <= CAPSEG;

    // Phase 3 (serial, ~nseg iters): fill position at each segment start
    if (tid == 0) {
        const int* S  = inLds ? (const int*)sS : (const int*)(wrow + 8);
        int*       Td = inLds ? sT : (wrow + 8 + (LSEQ + 2));
        int T = 0;
        for (int s = 0; s < count; ++s) {
            int p  = S[s];
            int pn = (s + 1 < count) ? S[s + 1] : LSEQ;
            int sl = pn - p;
            int c  = T & (PAGE - 1);
            if (c > 0 && (p == qp || sl > PAGE - c)) T += PAGE - c;  // flush pad
            Td[s] = T;
            T += sl;
        }
        sMeta[2] = T;
    }
    __syncthreads();

    // Export tables
    if (inLds) {
        for (int j = tid; j < count; j += 256) {
            wrow[8 + j]              = sS[j];
            wrow[8 + (LSEQ + 2) + j] = sT[j];
        }
    }
    if (tid == 0) { wrow[0] = count; wrow[1] = sMeta[1]; wrow[2] = sMeta[2]; }
}

// ---------------- fore: dependent region only ----------------

__global__ __launch_bounds__(256) void SegmentPager_fore(
        const int* __restrict__ mask,
        const int* __restrict__ ws,
        int* __restrict__ out) {
    __shared__ int sS[CAPSEG + 1];
    __shared__ int sT[CAPSEG + 1];

    const int row = blockIdx.x >> 3;     // SUBS == 8
    const int sub = blockIdx.x & 7;
    const int tid = threadIdx.x;

    const int* wrow = ws + (size_t)row * WROW;
    const int nseg = wrow[0];
    const int av   = wrow[1];
    const int Tend = av ? wrow[2] : 0;   // degenerate row: all background
    const int* gS = wrow + 8;
    const int* gT = wrow + 8 + (LSEQ + 2);

    const bool useLds = nseg <= CAPSEG;
    if (useLds)
        for (int j = tid; j < nseg; j += 256) { sS[j] = gS[j]; sT[j] = gT[j]; }
    __syncthreads();
    const int* S  = useLds ? (const int*)sS : gS;
    const int* Tt = useLds ? (const int*)sT : gT;
    const int* mkr = mask + (size_t)row * LSEQ;

    // ---- PI + PV over [0, TSAFE) ----
    int* pi = out + OFF_PI + (size_t)row * MP64;
    int* pv = out + OFF_PV + (size_t)row * MP64;
    const int Tbase = sub * SLOTS_SUB;
    for (int g = tid; g < SLOTS_SUB / 4; g += 256) {       // 514 groups
        int T = Tbase + g * 4;
        int4 vi = make_int4(-1, -1, -1, -1);
        int4 vv = make_int4(0, 0, 0, 0);
        if (T < Tend) {
            int r[4] = {-1, -1, -1, -1}, v[4] = {0, 0, 0, 0};
#pragma unroll
            for (int k = 0; k < 4; ++k) {
                int Tk = T + k;
                if (Tk < Tend) {
                    int lo = 0, hi = nseg - 1;
                    while (lo < hi) {                      // largest s: Tt[s] <= Tk
                        int mid = (lo + hi + 1) >> 1;
                        if (Tt[mid] <= Tk) lo = mid; else hi = mid - 1;
                    }
                    int pos  = S[lo] + (Tk - Tt[lo]);
                    int send = (lo + 1 < nseg) ? S[lo + 1] : LSEQ;
                    if (pos < send) { r[k] = pos; v[k] = (mkr[pos] != 0); }  // else pad
                }
            }
            vi = make_int4(r[0], r[1], r[2], r[3]);
            vv = make_int4(v[0], v[1], v[2], v[3]);
        }
        *(int4*)(pi + T) = vi;
        *(int4*)(pv + T) = vv;
    }

    // ---- SI pages [0, FOREPAGES): slot 0 of a live page is always a token ----
    if (sub == 0) {
        for (int p = tid; p < FOREPAGES; p += 256) {
            int T0 = p * PAGE;
            int sid = -1;
            if (T0 < Tend) {
                int lo = 0, hi = nseg - 1;
                while (lo < hi) {
                    int mid = (lo + hi + 1) >> 1;
                    if (Tt[mid] <= T0) lo = mid; else hi = mid - 1;
                }
                sid = lo;
            }
            out[OFF_SI + (size_t)row * MAXPAGES + p] = sid;
        }
    }

    // ---- TV + T2P ----
    for (int i = sub * TOK_SUB + tid; i < (sub + 1) * TOK_SUB; i += 256) {  // 4 iters
        out[OFF_TV + (size_t)row * LSEQ + i] = (mkr[i] != 0);
        int t2 = -1;
        if (av) {
            int lo = 0, hi = nseg - 1;
            while (lo < hi) {                              // largest s: S[s] <= i
                int mid = (lo + hi + 1) >> 1;
                if (S[mid] <= i) lo = mid; else hi = mid - 1;
            }
            t2 = (Tt[lo] + (i - S[lo])) >> 6;
        }
        out[OFF_T2P + (size_t)row * LSEQ + i] = t2;
    }
}

// ---------------- fallback path (round-1, known-good) ----------------

__global__ void SegmentPager_fill(int4* __restrict__ p) {
    const long long PI4  = (long long)BROWS * MP64 / 4;
    const long long PV4e = PI4 * 2;
    const long long N4   = PV4e + (long long)BROWS * MAXPAGES / 4;
    long long stride = (long long)gridDim.x * blockDim.x;
    for (long long i = (long long)blockIdx.x * blockDim.x + threadIdx.x;
         i < N4; i += stride) {
        int v = (i < PI4 || i >= PV4e) ? -1 : 0;
        p[i] = make_int4(v, v, v, v);
    }
}

__global__ __launch_bounds__(256) void SegmentPager_pager(
        const int* __restrict__ ids,
        const int* __restrict__ mask,
        const int* __restrict__ qpos,
        int* __restrict__ out) {
    __shared__ unsigned char sSt[LSEQ];
    __shared__ int sStarts[LSEQ + 2];
    __shared__ int sTst[LSEQ + 2];
    __shared__ int sMeta[2];

    const int row = blockIdx.x;
    const int tid = threadIdx.x;
    int qp = qpos[row];
    qp = qp < 0 ? 0 : (qp > LSEQ ? LSEQ : qp);

    const int* idr = ids  + (size_t)row * LSEQ;
    const int* mkr = mask + (size_t)row * LSEQ;

    if (tid < 2) sMeta[tid] = 0;
    __syncthreads();

    int myany = 0;
    for (int i = tid; i < LSEQ; i += 256) {
        int fl = (i == 0) || (i == qp);
        if (i > 0 && idr[i - 1] == 13) fl = 1;
        sSt[i] = (unsigned char)fl;
        myany |= (mkr[i] != 0);
    }
    if (myany) sMeta[1] = 1;
    __syncthreads();

    if (tid < 64) {
        int count = 0;
        for (int base = 0; base < LSEQ; base += 64) {
            bool f = sSt[base + tid] != 0;
            unsigned long long bal = __ballot(f);
            if (f) {
                int pre = __popcll(bal & ((1ull << tid) - 1ull));
                sStarts[count + pre] = base + tid;
            }
            count += __popcll(bal);
        }
        int T = 0;
        for (int s = 0; s < count; ++s) {
            int p  = sStarts[s];
            int pn = (s + 1 < count) ? sStarts[s + 1] : LSEQ;
            int sl = pn - p;
            int c  = T & (PAGE - 1);
            if (c > 0 && (p == qp || sl > PAGE - c)) T += PAGE - c;
            if (tid == 0) sTst[s] = T;
            T += sl;
        }
        if (tid == 0) sMeta[0] = count;
    }
    __syncthreads();

    const int nseg = sMeta[0];
    const int av   = sMeta[1];

    int* tv  = out + OFF_TV  + (size_t)row * LSEQ;
    int* t2p = out + OFF_T2P + (size_t)row * LSEQ;
    int* pi  = out + OFF_PI  + (size_t)row * MP64;
    int* pv  = out + OFF_PV  + (size_t)row * MP64;
    int* si  = out + OFF_SI  + (size_t)row * MAXPAGES;

    for (int i = tid; i < LSEQ; i += 256) {
        int lo = 0, hi = nseg - 1;
        while (lo < hi) {
            int mid = (lo + hi + 1) >> 1;
            if (sStarts[mid] <= i) lo = mid; else hi = mid - 1;
        }
        int T = sTst[lo] + (i - sStarts[lo]);
        int m = (mkr[i] != 0);
        tv[i]  = m;
        t2p[i] = av ? (T >> 6) : -1;
        if (av && T < MP64) {
            pi[T] = i;
            pv[T] = m;
            if ((T & (PAGE - 1)) == 0) si[T >> 6] = lo;
        }
    }
}

// ---------------- launch ----------------

extern "C" void kernel_launch(void* const* d_in, const int* in_sizes, int n_in,
                              void* d_out, int out_size, void* d_ws, size_t ws_size,
                              hipStream_t stream) {
    const int* ids  = (const int*)d_in[0];
    const int* mask = (const int*)d_in[1];
    const int* qpos = (const int*)d_in[2];
    int* out = (int*)d_out;

    if (ws_size >= WS_NEEDED && d_ws != nullptr) {
        int* ws = (int*)d_ws;
        SegmentPager_mega<<<BROWS + NBG, 256, 0, stream>>>(ids, mask, qpos, ws,
                                                           (int4*)(out + OFF_PI));
        SegmentPager_fore<<<BROWS * SUBS, 256, 0, stream>>>(mask, ws, out);
    } else {
        SegmentPager_fill<<<2048, 256, 0, stream>>>((int4*)(out + OFF_PI));
        SegmentPager_pager<<<BROWS, 256, 0, stream>>>(ids, mask, qpos, out);
    }
}